// Round 12
// baseline (60.024 us; speedup 1.0000x reference)
//
#include <hip/hip_runtime.h>
#include <hip/hip_bf16.h>
#include <math.h>

#define BB   8
#define CC   80
#define HH   128
#define WW   128
#define HWN  16384
#define KTOP 100
#define SCAP 2048       // >= 1849 theoretical per-map keep bound -> no key ever dropped
#define REGM 832        // per-map slab region (mean ~655; >832 -> sorted-top-832 fallback)

typedef unsigned long long ull;

__device__ __forceinline__ float sigmoidf_(float x) {
    // bitwise-matched vs jax.nn.sigmoid (R1/R3/R4/R6-R11)
    if (x >= 0.0f) return 1.0f / (1.0f + expf(-x));
    float e = expf(x);
    return e / (1.0f + e);
}

// value desc, class asc, hw asc; unique per (map,hw). Ordering == reference
// two-stage top-k (proof R2-R4, bitwise-validated through R11).
__device__ __forceinline__ ull makekey(float v, int cls, int hw) {
    return ((ull)__float_as_uint(v) << 21)
         | ((ull)(127 - cls) << 14)
         | (ull)(16383 - hw);
}

#define BITONIC_DESC(arr, N2, NTHR)                                         \
    for (int k_ = 2; k_ <= (N2); k_ <<= 1) {                                \
        for (int j_ = k_ >> 1; j_ > 0; j_ >>= 1) {                          \
            for (int i_ = threadIdx.x; i_ < (N2); i_ += (NTHR)) {           \
                const int ixj_ = i_ ^ j_;                                   \
                if (ixj_ > i_) {                                            \
                    ull a_ = (arr)[i_], b_ = (arr)[ixj_];                   \
                    if (((i_ & k_) == 0) ? (a_ < b_) : (a_ > b_)) {         \
                        (arr)[i_] = b_; (arr)[ixj_] = a_;                   \
                    }                                                       \
                }                                                           \
            }                                                               \
            __syncthreads();                                                \
        }                                                                   \
    }

// ---- Kernel A: barrier-free NMS — rolling-register V-max + shfl H-max ----
// Block = one map. Thread (qc = tid&31, band = tid>>5) owns quad-column qc,
// rows [16*band, 16*band+16). 20 coalesced float4 loads, sigma in regs,
// 5-row rolling max (f[k%5], k compile-time), H-max via lane+-1 shfl
// (lanes 0-31 = band 2w, 32-63 = band 2w+1; qc edges masked to -inf).
__global__ __launch_bounds__(256) void knms(const float* __restrict__ logits,
                                            ull* __restrict__ slab,
                                            int* __restrict__ scount) {
    __shared__ ull cand[SCAP];                   // 16 KB
    __shared__ int cnt;

    const int tid  = threadIdx.x;
    const int map  = blockIdx.x;                 // b*CC + c
    const int cls  = map % CC;
    const int qc   = tid & 31;
    const int band = tid >> 5;                   // 0..7
    const int lane = tid & 63;
    const int R0   = band << 4;
    const int c0   = qc << 2;
    const float* __restrict__ src = logits + (size_t)map * HWN + c0;
    if (tid == 0) cnt = 0;
    __syncthreads();

    float4 f[5];
    // prologue: rows R0-2 .. R0+1 (top-clamped; only band 0 clamps)
#pragma unroll
    for (int k = 0; k < 4; ++k) {
        int gr = R0 - 2 + k;
        gr = gr < 0 ? 0 : gr;
        const float4 raw = *reinterpret_cast<const float4*>(src + (size_t)gr * WW);
        float4 o;
        o.x = sigmoidf_(raw.x); o.y = sigmoidf_(raw.y);
        o.z = sigmoidf_(raw.z); o.w = sigmoidf_(raw.w);
        f[k] = o;
    }
    // steady state: load row R0-2+k, finalize output row R0+k-4
#pragma unroll
    for (int k = 4; k < 20; ++k) {
        int gr = R0 - 2 + k;                     // >= 2, bottom-clamp only
        gr = gr > HH - 1 ? HH - 1 : gr;
        const float4 raw = *reinterpret_cast<const float4*>(src + (size_t)gr * WW);
        float4 o;
        o.x = sigmoidf_(raw.x); o.y = sigmoidf_(raw.y);
        o.z = sigmoidf_(raw.z); o.w = sigmoidf_(raw.w);
        f[k % 5] = o;

        // vertical 5-max across the rolling window (rows k-4..k)
        float4 vm;
        vm.x = fmaxf(fmaxf(f[0].x, f[1].x), fmaxf(fmaxf(f[2].x, f[3].x), f[4].x));
        vm.y = fmaxf(fmaxf(f[0].y, f[1].y), fmaxf(fmaxf(f[2].y, f[3].y), f[4].y));
        vm.z = fmaxf(fmaxf(f[0].z, f[1].z), fmaxf(fmaxf(f[2].z, f[3].z), f[4].z));
        vm.w = fmaxf(fmaxf(f[0].w, f[1].w), fmaxf(fmaxf(f[2].w, f[3].w), f[4].w));
        const float4 cen = f[(k - 2) % 5];       // center row of the window

        // neighbor-quad V-max via shfl (garbage at band seams masked by qc test)
        float Lz = __shfl(vm.z, lane - 1, 64);
        float Lw = __shfl(vm.w, lane - 1, 64);
        float Rx = __shfl(vm.x, lane + 1, 64);
        float Ry = __shfl(vm.y, lane + 1, 64);
        if (qc == 0)  { Lz = -INFINITY; Lw = -INFINITY; }
        if (qc == 31) { Rx = -INFINITY; Ry = -INFINITY; }

        const float mxy = fmaxf(vm.x, vm.y), mzw = fmaxf(vm.z, vm.w);
        const float m0 = fmaxf(fmaxf(Lz, Lw), fmaxf(mxy, vm.z));
        const float m1 = fmaxf(Lw, fmaxf(mxy, mzw));
        const float m2 = fmaxf(fmaxf(mxy, mzw), Rx);
        const float m3 = fmaxf(fmaxf(vm.y, mzw), fmaxf(Rx, Ry));
        const int hwb = ((R0 + k - 4) << 7) | c0;
        if (cen.x == m0) { const int t = atomicAdd(&cnt, 1); if (t < SCAP) cand[t] = makekey(cen.x, cls, hwb); }
        if (cen.y == m1) { const int t = atomicAdd(&cnt, 1); if (t < SCAP) cand[t] = makekey(cen.y, cls, hwb + 1); }
        if (cen.z == m2) { const int t = atomicAdd(&cnt, 1); if (t < SCAP) cand[t] = makekey(cen.z, cls, hwb + 2); }
        if (cen.w == m3) { const int t = atomicAdd(&cnt, 1); if (t < SCAP) cand[t] = makekey(cen.w, cls, hwb + 3); }
    }
    __syncthreads();

    const int n = cnt;                           // <= 1849 < SCAP, nothing dropped
    ull* __restrict__ dst = slab + (size_t)map * REGM;
    if (n <= REGM) {
        // common path (n ~655): unsorted write + count
        for (int i = tid; i < n; i += 256) dst[i] = cand[i];
        if (tid == 0) scount[map] = n;
    } else {
        // rare fallback: exact lex sort, write top-REGM (superset of map top-100)
        int n2 = 1024;
        while (n2 < n) n2 <<= 1;
        for (int i = tid; i < n2; i += 256) if (i >= n) cand[i] = 0ULL;
        __syncthreads();
        BITONIC_DESC(cand, n2, 256);
        for (int i = tid; i < REGM; i += 256) dst[i] = cand[i];
        if (tid == 0) scount[map] = REGM;
    }
}

// ---- in-register wave bitonic helpers (64 lanes; R6-R11 validated) ----
__device__ __forceinline__ ull sort64_desc(ull v, int lane) {
    for (int k = 2; k <= 64; k <<= 1) {
        for (int j = k >> 1; j >= 1; j >>= 1) {
            const ull p = __shfl_xor(v, j, 64);
            const bool km = (((lane & k) == 0) != ((lane & j) != 0));
            v = (km == (p > v)) ? p : v;
        }
    }
    return v;
}

__device__ __forceinline__ void bmerge128(ull& a0, ull& a1, int lane) {
    const ull t0 = a0 > a1 ? a0 : a1;
    a1 = a0 > a1 ? a1 : a0;
    a0 = t0;
    for (int j = 32; j >= 1; j >>= 1) {
        const ull p0 = __shfl_xor(a0, j, 64);
        const ull p1 = __shfl_xor(a1, j, 64);
        const bool km = ((lane & j) == 0);
        a0 = (km == (p0 > a0)) ? p0 : a0;
        a1 = (km == (p1 > a1)) ? p1 : a1;
    }
}

// ---- Kernel B: per map (640 blocks): 8 waves stream 16 chunks -> map top-128 ----
__global__ __launch_bounds__(512) void kred(const ull* __restrict__ slab,
                                            const int* __restrict__ scount,
                                            ull* __restrict__ lists) {
    __shared__ ull ls[8][128];
    const int tid = threadIdx.x, w = tid >> 6, lane = tid & 63;
    const int map = blockIdx.x;

    const int n = scount[map];                   // <= REGM = 832 = 13 chunks
    const ull* __restrict__ base = slab + (size_t)map * REGM;

    ull a0 = 0ULL, a1 = 0ULL;
#pragma unroll
    for (int c = 0; c < 2; ++c) {                // chunks w, w+8 -> covers 0..15
        const int idx = (w + c * 8) * 64 + lane;
        ull v = (idx < n) ? base[idx] : 0ULL;
        v = sort64_desc(v, lane);
        const ull rv = __shfl(v, 63 - lane, 64);
        a1 = a1 > rv ? a1 : rv;
        bmerge128(a0, a1, lane);
    }
    ls[w][lane] = a0;
    ls[w][64 + lane] = a1;

    for (int half = 4; half >= 1; half >>= 1) {
        __syncthreads();
        ull z0 = 0ULL, z1 = 0ULL;
        const bool act = (w < half);
        if (act) {
            const ull l0 = ls[2 * w][lane];
            const ull l1 = ls[2 * w][64 + lane];
            const ull r1r = ls[2 * w + 1][127 - lane];
            const ull r0r = ls[2 * w + 1][63 - lane];
            z0 = l0 > r1r ? l0 : r1r;
            z1 = l1 > r0r ? l1 : r0r;
            bmerge128(z0, z1, lane);
        }
        __syncthreads();
        if (act) { ls[w][lane] = z0; ls[w][64 + lane] = z1; }
    }
    __syncthreads();
    if (tid < 128)
        lists[(size_t)map * 128 + tid] = ls[0][tid];
}

// ---- Kernel C: per batch: 16 waves reg-merge 5 map-lists each, tree, decode ----
__global__ __launch_bounds__(1024) void kfin(const ull* __restrict__ lists,
                                             const float* __restrict__ txty,
                                             const float* __restrict__ twth,
                                             float* __restrict__ out) {
    __shared__ ull ls[16][128];                  // 16 KB
    const int tid = threadIdx.x, b = blockIdx.x;
    const int w = tid >> 6, lane = tid & 63;
    const ull* __restrict__ L = lists + (size_t)b * CC * 128;

    const ull* __restrict__ l0 = L + (size_t)(5 * w) * 128;
    ull a0 = l0[lane], a1 = l0[64 + lane];
#pragma unroll
    for (int k = 1; k < 5; ++k) {
        const ull* __restrict__ lk = L + (size_t)(5 * w + k) * 128;
        const ull r0 = lk[127 - lane];
        const ull r1 = lk[63 - lane];
        a0 = a0 > r0 ? a0 : r0;
        a1 = a1 > r1 ? a1 : r1;
        bmerge128(a0, a1, lane);
    }
    ls[w][lane] = a0;
    ls[w][64 + lane] = a1;

    for (int half = 8; half >= 1; half >>= 1) {
        __syncthreads();
        ull z0 = 0ULL, z1 = 0ULL;
        const bool act = (w < half);
        if (act) {
            const ull t0 = ls[2 * w][lane];
            const ull t1 = ls[2 * w][64 + lane];
            const ull r1r = ls[2 * w + 1][127 - lane];
            const ull r0r = ls[2 * w + 1][63 - lane];
            z0 = t0 > r1r ? t0 : r1r;
            z1 = t1 > r0r ? t1 : r0r;
            bmerge128(z0, z1, lane);
        }
        __syncthreads();
        if (act) { ls[w][lane] = z0; ls[w][64 + lane] = z1; }
    }
    __syncthreads();

    if (tid < KTOP) {
        const ull key = ls[0][tid];
        const int hw  = 16383 - (int)(key & 0x3FFFULL);
        const int cls = 127 - (int)((key >> 14) & 0x7FULL);
        const float sc = __uint_as_float((unsigned int)(key >> 21));

        // out layout (float32): score[0..800) | bbox[800..4000) | inds[4000..4800) | clses[4800..5600)
        out[b * KTOP + tid]        = sc;
        out[4000 + b * KTOP + tid] = (float)hw;
        out[4800 + b * KTOP + tid] = (float)cls;

        const int xx = hw & 127, yy = hw >> 7;
        const float* __restrict__ t = txty + (size_t)b * 2 * HWN;
        const float* __restrict__ u = twth + (size_t)b * 2 * HWN;
        const float tx = t[hw], ty = t[HWN + hw];
        const float tw = u[hw], th = u[HWN + hw];

        const float cx = (sigmoidf_(tx) + (float)xx) * 4.0f;
        const float cy = (sigmoidf_(ty) + (float)yy) * 4.0f;
        const float bw = expf(tw) * 4.0f;
        const float bh = expf(th) * 4.0f;

        const float inv = 1.0f / 512.0f;
        float x1 = (cx - bw * 0.5f) * inv;
        float y1 = (cy - bh * 0.5f) * inv;
        float x2 = (cx + bw * 0.5f) * inv;
        float y2 = (cy + bh * 0.5f) * inv;
        x1 = fminf(fmaxf(x1, 0.0f), 1.0f);
        y1 = fminf(fmaxf(y1, 0.0f), 1.0f);
        x2 = fminf(fmaxf(x2, 0.0f), 1.0f);
        y2 = fminf(fmaxf(y2, 0.0f), 1.0f);

        float* bb = out + 800 + (size_t)(b * KTOP + tid) * 4;
        bb[0] = x1; bb[1] = y1; bb[2] = x2; bb[3] = y2;
    }
}

extern "C" void kernel_launch(void* const* d_in, const int* in_sizes, int n_in,
                              void* d_out, int out_size, void* d_ws, size_t ws_size,
                              hipStream_t stream) {
    const float* cls_logits = (const float*)d_in[0];
    const float* txty       = (const float*)d_in[1];
    const float* twth       = (const float*)d_in[2];
    float* out = (float*)d_out;

    // ws layout (bytes):
    //   slab:   640 maps * 832 * 8 = 4,259,840
    //   scount: 640 * 4            =     2,560   @ 4,259,840
    //   lists:  640 * 128 * 8      =   655,360   @ 4,262,400
    // total 4,917,760 — every byte read is written first (no memset needed)
    ull* slab   = (ull*)d_ws;
    int* scount = (int*)((char*)d_ws + 4259840);
    ull* lists  = (ull*)((char*)d_ws + 4262400);

    knms<<<BB * CC, 256, 0, stream>>>(cls_logits, slab, scount);
    kred<<<BB * CC, 512, 0, stream>>>(slab, scount, lists);
    kfin<<<BB,     1024, 0, stream>>>(lists, txty, twth, out);
}

// Round 13
// 57.575 us; speedup vs baseline: 1.0426x; 1.0426x over previous
//
#include <hip/hip_runtime.h>
#include <hip/hip_bf16.h>
#include <math.h>

#define BB   8
#define CC   80
#define HH   128
#define WW   128
#define HWN  16384
#define KTOP 100
#define NSTRIP 8
#define SR   16
#define LR   (SR + 4)
#define SCAP 512
#define REG  100        // fixed per-strip region: strip lex-top-100 superset-suffices

typedef unsigned long long ull;

__device__ __forceinline__ float sigmoidf_(float x) {
    // bitwise-matched vs jax.nn.sigmoid (R1/R3/R4/R6-R12)
    if (x >= 0.0f) return 1.0f / (1.0f + expf(-x));
    float e = expf(x);
    return e / (1.0f + e);
}

// value desc, class asc, hw asc; unique per (map,hw). Ordering == reference
// two-stage top-k (proof R2-R4, bitwise-validated through R12).
__device__ __forceinline__ ull makekey(float v, int cls, int hw) {
    return ((ull)__float_as_uint(v) << 21)
         | ((ull)(127 - cls) << 14)
         | (ull)(16383 - hw);
}

#define BITONIC_DESC(arr, N2, NTHR)                                         \
    for (int k_ = 2; k_ <= (N2); k_ <<= 1) {                                \
        for (int j_ = k_ >> 1; j_ > 0; j_ >>= 1) {                          \
            for (int i_ = threadIdx.x; i_ < (N2); i_ += (NTHR)) {           \
                const int ixj_ = i_ ^ j_;                                   \
                if (ixj_ > i_) {                                            \
                    ull a_ = (arr)[i_], b_ = (arr)[ixj_];                   \
                    if (((i_ & k_) == 0) ? (a_ < b_) : (a_ > b_)) {         \
                        (arr)[i_] = b_; (arr)[ixj_] = a_;                   \
                    }                                                       \
                }                                                           \
            }                                                               \
            __syncthreads();                                                \
        }                                                                   \
    }

// ---- Kernel A: 2-barrier NMS — stage sigmoid, fused V+H window max ----
// R11 base (no global atomics, fixed-region write). vm[] LDS array deleted:
// V-max of the 3 quad-cols is built in registers from 15 b128 reads.
// LDS 23KB -> 14.4KB lifts the blocks/CU cap 6 -> 8 (wave-capped).
__global__ __launch_bounds__(256) void knms(const float* __restrict__ logits,
                                            ull* __restrict__ slab,
                                            int* __restrict__ scount) {
    __shared__ __align__(16) float s[LR][WW];    // 10 KB sigmoid tile (halo-clamped)
    __shared__ ull cand[SCAP];                   // 4 KB
    __shared__ int cnt;

    const int tid   = threadIdx.x;
    const int map   = blockIdx.x >> 3;           // b*CC + c
    const int strip = blockIdx.x & 7;
    const int cls   = map % CC;
    const int R0    = strip * SR;
    const float* __restrict__ src = logits + (size_t)map * HWN;
    if (tid == 0) cnt = 0;

    // stage sigmoid tile, float4, halo rows clamped (== -inf pad for window max)
    for (int v = tid; v < LR * 32; v += 256) {
        const int lr = v >> 5, c4 = (v & 31) << 2;
        int gr = R0 - 2 + lr;
        gr = gr < 0 ? 0 : (gr > HH - 1 ? HH - 1 : gr);
        const float4 f = *reinterpret_cast<const float4*>(src + (size_t)gr * WW + c4);
        float4 o;
        o.x = sigmoidf_(f.x); o.y = sigmoidf_(f.y);
        o.z = sigmoidf_(f.z); o.w = sigmoidf_(f.w);
        *reinterpret_cast<float4*>(&s[lr][c4]) = o;
    }
    __syncthreads();

    // fused V+H: per center quad, accumulate V-max of L/M/R quad-cols over the
    // 5 window rows in registers (named scalars; no arrays -> no scratch)
    for (int i = tid; i < SR * 32; i += 256) {
        const int r = i >> 5, c4 = (i & 31) << 2;
        const bool hasL = (c4 >= 4), hasR = (c4 <= WW - 8);
        float mLz = -INFINITY, mLw = -INFINITY;
        float mMx = -INFINITY, mMy = -INFINITY, mMz = -INFINITY, mMw = -INFINITY;
        float mRx = -INFINITY, mRy = -INFINITY;
        float cenx = 0.f, ceny = 0.f, cenz = 0.f, cenw = 0.f;
#pragma unroll
        for (int rr = 0; rr < 5; ++rr) {
            const float4 M = *reinterpret_cast<const float4*>(&s[r + rr][c4]);
            mMx = fmaxf(mMx, M.x); mMy = fmaxf(mMy, M.y);
            mMz = fmaxf(mMz, M.z); mMw = fmaxf(mMw, M.w);
            if (rr == 2) { cenx = M.x; ceny = M.y; cenz = M.z; cenw = M.w; }
            if (hasL) {
                const float4 L = *reinterpret_cast<const float4*>(&s[r + rr][c4 - 4]);
                mLz = fmaxf(mLz, L.z); mLw = fmaxf(mLw, L.w);
            }
            if (hasR) {
                const float4 R = *reinterpret_cast<const float4*>(&s[r + rr][c4 + 4]);
                mRx = fmaxf(mRx, R.x); mRy = fmaxf(mRy, R.y);
            }
        }
        const float mxy = fmaxf(mMx, mMy), mzw = fmaxf(mMz, mMw);
        const float m0 = fmaxf(fmaxf(mLz, mLw), fmaxf(mxy, mMz));
        const float m1 = fmaxf(mLw, fmaxf(mxy, mzw));
        const float m2 = fmaxf(fmaxf(mxy, mzw), mRx);
        const float m3 = fmaxf(fmaxf(mMy, mzw), fmaxf(mRx, mRy));
        const int hwb = ((R0 + r) << 7) | c4;
        if (cenx == m0) { const int t = atomicAdd(&cnt, 1); if (t < SCAP) cand[t] = makekey(cenx, cls, hwb); }
        if (ceny == m1) { const int t = atomicAdd(&cnt, 1); if (t < SCAP) cand[t] = makekey(ceny, cls, hwb + 1); }
        if (cenz == m2) { const int t = atomicAdd(&cnt, 1); if (t < SCAP) cand[t] = makekey(cenz, cls, hwb + 2); }
        if (cenw == m3) { const int t = atomicAdd(&cnt, 1); if (t < SCAP) cand[t] = makekey(cenw, cls, hwb + 3); }
    }
    __syncthreads();

    const int n = cnt < SCAP ? cnt : SCAP;
    ull* __restrict__ dst = slab + (size_t)blockIdx.x * REG;
    if (n <= REG) {
        // fast path (n~82): unsorted write + count — no global atomics (R11 lesson)
        for (int i = tid; i < n; i += 256) dst[i] = cand[i];
        if (tid == 0) scount[blockIdx.x] = n;
    } else {
        // rare path: exact lex-top-100 via in-LDS bitonic (R4-proven)
        int n2 = 128;
        while (n2 < n) n2 <<= 1;
        for (int i = tid; i < n2; i += 256) if (i >= n) cand[i] = 0ULL;
        __syncthreads();
        BITONIC_DESC(cand, n2, 256);
        for (int i = tid; i < REG; i += 256) dst[i] = cand[i];
        if (tid == 0) scount[blockIdx.x] = REG;
    }
}

// ---- in-register wave bitonic helpers (64 lanes; R6-R12 validated) ----
__device__ __forceinline__ ull sort64_desc(ull v, int lane) {
    for (int k = 2; k <= 64; k <<= 1) {
        for (int j = k >> 1; j >= 1; j >>= 1) {
            const ull p = __shfl_xor(v, j, 64);
            const bool km = (((lane & k) == 0) != ((lane & j) != 0));
            v = (km == (p > v)) ? p : v;
        }
    }
    return v;
}

__device__ __forceinline__ void bmerge128(ull& a0, ull& a1, int lane) {
    const ull t0 = a0 > a1 ? a0 : a1;
    a1 = a0 > a1 ? a1 : a0;
    a0 = t0;
    for (int j = 32; j >= 1; j >>= 1) {
        const ull p0 = __shfl_xor(a0, j, 64);
        const ull p1 = __shfl_xor(a1, j, 64);
        const bool km = ((lane & j) == 0);
        a0 = (km == (p0 > a0)) ? p0 : a0;
        a1 = (km == (p1 > a1)) ? p1 : a1;
    }
}

// ---- Kernel B: per map (640 blocks): 8 waves sort one strip each, merge -> top-128 ----
__global__ __launch_bounds__(512) void kred(const ull* __restrict__ slab,
                                            const int* __restrict__ scount,
                                            ull* __restrict__ lists) {
    __shared__ ull ls[8][128];
    const int tid = threadIdx.x, w = tid >> 6, lane = tid & 63;
    const int map = blockIdx.x;
    const int sg = map * NSTRIP + w;             // global strip id for this wave

    const int n = scount[sg];
    const ull* __restrict__ base = slab + (size_t)sg * REG;

    ull a0 = 0ULL, a1 = 0ULL;
#pragma unroll
    for (int c = 0; c < 2; ++c) {
        const int idx = c * 64 + lane;
        ull v = (idx < n) ? base[idx] : 0ULL;
        v = sort64_desc(v, lane);
        const ull rv = __shfl(v, 63 - lane, 64);
        a1 = a1 > rv ? a1 : rv;
        bmerge128(a0, a1, lane);
    }
    ls[w][lane] = a0;
    ls[w][64 + lane] = a1;

    for (int half = 4; half >= 1; half >>= 1) {
        __syncthreads();
        ull z0 = 0ULL, z1 = 0ULL;
        const bool act = (w < half);
        if (act) {
            const ull l0 = ls[2 * w][lane];
            const ull l1 = ls[2 * w][64 + lane];
            const ull r1r = ls[2 * w + 1][127 - lane];
            const ull r0r = ls[2 * w + 1][63 - lane];
            z0 = l0 > r1r ? l0 : r1r;
            z1 = l1 > r0r ? l1 : r0r;
            bmerge128(z0, z1, lane);
        }
        __syncthreads();
        if (act) { ls[w][lane] = z0; ls[w][64 + lane] = z1; }
    }
    __syncthreads();
    if (tid < 128)
        lists[(size_t)map * 128 + tid] = ls[0][tid];
}

// ---- Kernel C: per batch: 16 waves reg-merge 5 map-lists each, tree, decode ----
__global__ __launch_bounds__(1024) void kfin(const ull* __restrict__ lists,
                                             const float* __restrict__ txty,
                                             const float* __restrict__ twth,
                                             float* __restrict__ out) {
    __shared__ ull ls[16][128];                  // 16 KB
    const int tid = threadIdx.x, b = blockIdx.x;
    const int w = tid >> 6, lane = tid & 63;
    const ull* __restrict__ L = lists + (size_t)b * CC * 128;

    const ull* __restrict__ l0 = L + (size_t)(5 * w) * 128;
    ull a0 = l0[lane], a1 = l0[64 + lane];
#pragma unroll
    for (int k = 1; k < 5; ++k) {
        const ull* __restrict__ lk = L + (size_t)(5 * w + k) * 128;
        const ull r0 = lk[127 - lane];
        const ull r1 = lk[63 - lane];
        a0 = a0 > r0 ? a0 : r0;
        a1 = a1 > r1 ? a1 : r1;
        bmerge128(a0, a1, lane);
    }
    ls[w][lane] = a0;
    ls[w][64 + lane] = a1;

    for (int half = 8; half >= 1; half >>= 1) {
        __syncthreads();
        ull z0 = 0ULL, z1 = 0ULL;
        const bool act = (w < half);
        if (act) {
            const ull t0 = ls[2 * w][lane];
            const ull t1 = ls[2 * w][64 + lane];
            const ull r1r = ls[2 * w + 1][127 - lane];
            const ull r0r = ls[2 * w + 1][63 - lane];
            z0 = t0 > r1r ? t0 : r1r;
            z1 = t1 > r0r ? t1 : r0r;
            bmerge128(z0, z1, lane);
        }
        __syncthreads();
        if (act) { ls[w][lane] = z0; ls[w][64 + lane] = z1; }
    }
    __syncthreads();

    if (tid < KTOP) {
        const ull key = ls[0][tid];
        const int hw  = 16383 - (int)(key & 0x3FFFULL);
        const int cls = 127 - (int)((key >> 14) & 0x7FULL);
        const float sc = __uint_as_float((unsigned int)(key >> 21));

        // out layout (float32): score[0..800) | bbox[800..4000) | inds[4000..4800) | clses[4800..5600)
        out[b * KTOP + tid]        = sc;
        out[4000 + b * KTOP + tid] = (float)hw;
        out[4800 + b * KTOP + tid] = (float)cls;

        const int xx = hw & 127, yy = hw >> 7;
        const float* __restrict__ t = txty + (size_t)b * 2 * HWN;
        const float* __restrict__ u = twth + (size_t)b * 2 * HWN;
        const float tx = t[hw], ty = t[HWN + hw];
        const float tw = u[hw], th = u[HWN + hw];

        const float cx = (sigmoidf_(tx) + (float)xx) * 4.0f;
        const float cy = (sigmoidf_(ty) + (float)yy) * 4.0f;
        const float bw = expf(tw) * 4.0f;
        const float bh = expf(th) * 4.0f;

        const float inv = 1.0f / 512.0f;
        float x1 = (cx - bw * 0.5f) * inv;
        float y1 = (cy - bh * 0.5f) * inv;
        float x2 = (cx + bw * 0.5f) * inv;
        float y2 = (cy + bh * 0.5f) * inv;
        x1 = fminf(fmaxf(x1, 0.0f), 1.0f);
        y1 = fminf(fmaxf(y1, 0.0f), 1.0f);
        x2 = fminf(fmaxf(x2, 0.0f), 1.0f);
        y2 = fminf(fmaxf(y2, 0.0f), 1.0f);

        float* bb = out + 800 + (size_t)(b * KTOP + tid) * 4;
        bb[0] = x1; bb[1] = y1; bb[2] = x2; bb[3] = y2;
    }
}

extern "C" void kernel_launch(void* const* d_in, const int* in_sizes, int n_in,
                              void* d_out, int out_size, void* d_ws, size_t ws_size,
                              hipStream_t stream) {
    const float* cls_logits = (const float*)d_in[0];
    const float* txty       = (const float*)d_in[1];
    const float* twth       = (const float*)d_in[2];
    float* out = (float*)d_out;

    // ws layout (bytes):
    //   slab:   5120 strips * 100 * 8 = 4,096,000
    //   scount: 5120 * 4             =    20,480   @ 4,096,000
    //   lists:  640 * 128 * 8        =   655,360   @ 4,116,480
    // total 4,771,840 — every byte read is written first (no memset needed)
    ull* slab   = (ull*)d_ws;
    int* scount = (int*)((char*)d_ws + 4096000);
    ull* lists  = (ull*)((char*)d_ws + 4116480);

    knms<<<BB * CC * NSTRIP, 256, 0, stream>>>(cls_logits, slab, scount);
    kred<<<BB * CC,          512, 0, stream>>>(slab, scount, lists);
    kfin<<<BB,              1024, 0, stream>>>(lists, txty, twth, out);
}

// Round 14
// 57.485 us; speedup vs baseline: 1.0442x; 1.0016x over previous
//
#include <hip/hip_runtime.h>
#include <hip/hip_bf16.h>
#include <math.h>

#define BB   8
#define CC   80
#define HH   128
#define WW   128
#define HWN  16384
#define KTOP 100
#define NSTRIP 8
#define SR   16
#define LR   (SR + 4)
#define SCAP 512
#define REG  100        // fixed per-strip region: strip lex-top-100 superset-suffices

typedef unsigned long long ull;

__device__ __forceinline__ float sigmoidf_(float x) {
    // bitwise-matched vs jax.nn.sigmoid (R1/R3/R4/R6-R13)
    if (x >= 0.0f) return 1.0f / (1.0f + expf(-x));
    float e = expf(x);
    return e / (1.0f + e);
}

// value desc, class asc, hw asc; unique per (map,hw). Ordering == reference
// two-stage top-k (proof R2-R4, bitwise-validated through R13).
__device__ __forceinline__ ull makekey(float v, int cls, int hw) {
    return ((ull)__float_as_uint(v) << 21)
         | ((ull)(127 - cls) << 14)
         | (ull)(16383 - hw);
}

#define BITONIC_DESC(arr, N2, NTHR)                                         \
    for (int k_ = 2; k_ <= (N2); k_ <<= 1) {                                \
        for (int j_ = k_ >> 1; j_ > 0; j_ >>= 1) {                          \
            for (int i_ = threadIdx.x; i_ < (N2); i_ += (NTHR)) {           \
                const int ixj_ = i_ ^ j_;                                   \
                if (ixj_ > i_) {                                            \
                    ull a_ = (arr)[i_], b_ = (arr)[ixj_];                   \
                    if (((i_ & k_) == 0) ? (a_ < b_) : (a_ > b_)) {         \
                        (arr)[i_] = b_; (arr)[ixj_] = a_;                   \
                    }                                                       \
                }                                                           \
            }                                                               \
            __syncthreads();                                                \
        }                                                                   \
    }

// ---- Kernel A: dual-strip T14 pipeline ----
// Block = 2 adjacent strips of one map. B-strip's global loads are issued at
// kernel top (registers), sharing one HBM-latency window with A's staging;
// B's tile write happens after A's compute -> one stall per 2 strips.
__global__ __launch_bounds__(256) void knms(const float* __restrict__ logits,
                                            ull* __restrict__ slab,
                                            int* __restrict__ scount) {
    __shared__ __align__(16) float s[LR][WW];    // 10 KB sigmoid tile
    __shared__ __align__(16) float vm[SR][WW];   // 8 KB vertical 5-max
    __shared__ ull cand[SCAP];                   // 4 KB
    __shared__ int cntA, cntB;

    const int tid  = threadIdx.x;
    const int map  = blockIdx.x >> 2;            // b*CC + c
    const int pair = blockIdx.x & 3;
    const int cls  = map % CC;
    const int R0A  = pair << 5;                  // 32*pair
    const int R0B  = R0A + SR;
    const float* __restrict__ src = logits + (size_t)map * HWN;
    if (tid == 0) { cntA = 0; cntB = 0; }

    // P0: issue strip-B loads into registers (in flight through A's staging)
    float4 g0, g1, g2;
    {
        const int v0 = tid, v1 = tid + 256, v2 = tid + 512;
        int gr0 = R0B - 2 + (v0 >> 5); gr0 = gr0 > HH - 1 ? HH - 1 : gr0;
        int gr1 = R0B - 2 + (v1 >> 5); gr1 = gr1 > HH - 1 ? HH - 1 : gr1;
        int gr2 = R0B - 2 + (v2 >> 5); gr2 = gr2 > HH - 1 ? HH - 1 : gr2;
        g0 = *reinterpret_cast<const float4*>(src + (size_t)gr0 * WW + ((v0 & 31) << 2));
        g1 = *reinterpret_cast<const float4*>(src + (size_t)gr1 * WW + ((v1 & 31) << 2));
        g2 = (tid < 128)
           ? *reinterpret_cast<const float4*>(src + (size_t)gr2 * WW + ((v2 & 31) << 2))
           : make_float4(0.f, 0.f, 0.f, 0.f);
    }

    // P1: stage strip A (load + sigmoid + LDS write)
    for (int v = tid; v < LR * 32; v += 256) {
        const int lr = v >> 5, c4 = (v & 31) << 2;
        int gr = R0A - 2 + lr;
        gr = gr < 0 ? 0 : (gr > HH - 1 ? HH - 1 : gr);
        const float4 f = *reinterpret_cast<const float4*>(src + (size_t)gr * WW + c4);
        float4 o;
        o.x = sigmoidf_(f.x); o.y = sigmoidf_(f.y);
        o.z = sigmoidf_(f.z); o.w = sigmoidf_(f.w);
        *reinterpret_cast<float4*>(&s[lr][c4]) = o;
    }
    __syncthreads();

    // P2: vertical 5-max A (quad b128)
    for (int i = tid; i < SR * 32; i += 256) {
        const int r = i >> 5, c4 = (i & 31) << 2;
        const float4 r0 = *reinterpret_cast<const float4*>(&s[r    ][c4]);
        const float4 r1 = *reinterpret_cast<const float4*>(&s[r + 1][c4]);
        const float4 r2 = *reinterpret_cast<const float4*>(&s[r + 2][c4]);
        const float4 r3 = *reinterpret_cast<const float4*>(&s[r + 3][c4]);
        const float4 r4 = *reinterpret_cast<const float4*>(&s[r + 4][c4]);
        float4 m;
        m.x = fmaxf(fmaxf(r0.x, r1.x), fmaxf(fmaxf(r2.x, r3.x), r4.x));
        m.y = fmaxf(fmaxf(r0.y, r1.y), fmaxf(fmaxf(r2.y, r3.y), r4.y));
        m.z = fmaxf(fmaxf(r0.z, r1.z), fmaxf(fmaxf(r2.z, r3.z), r4.z));
        m.w = fmaxf(fmaxf(r0.w, r1.w), fmaxf(fmaxf(r2.w, r3.w), r4.w));
        *reinterpret_cast<float4*>(&vm[r][c4]) = m;
    }
    __syncthreads();

    // P3: horizontal 5-max A + keep + compact (named scalars only)
    for (int i = tid; i < SR * 32; i += 256) {
        const int r = i >> 5, c4 = (i & 31) << 2;
        const float4 M = *reinterpret_cast<const float4*>(&vm[r][c4]);
        float Lz = -INFINITY, Lw = -INFINITY;
        if (c4 >= 4) {
            const float4 L = *reinterpret_cast<const float4*>(&vm[r][c4 - 4]);
            Lz = L.z; Lw = L.w;
        }
        float Rx = -INFINITY, Ry = -INFINITY;
        if (c4 <= WW - 8) {
            const float4 R = *reinterpret_cast<const float4*>(&vm[r][c4 + 4]);
            Rx = R.x; Ry = R.y;
        }
        const float4 cen = *reinterpret_cast<const float4*>(&s[r + 2][c4]);
        const float mxy = fmaxf(M.x, M.y), mzw = fmaxf(M.z, M.w);
        const float m0 = fmaxf(fmaxf(Lz, Lw), fmaxf(mxy, M.z));
        const float m1 = fmaxf(Lw, fmaxf(mxy, mzw));
        const float m2 = fmaxf(fmaxf(mxy, mzw), Rx);
        const float m3 = fmaxf(fmaxf(M.y, mzw), fmaxf(Rx, Ry));
        const int hwb = ((R0A + r) << 7) | c4;
        if (cen.x == m0) { const int t = atomicAdd(&cntA, 1); if (t < SCAP) cand[t] = makekey(cen.x, cls, hwb); }
        if (cen.y == m1) { const int t = atomicAdd(&cntA, 1); if (t < SCAP) cand[t] = makekey(cen.y, cls, hwb + 1); }
        if (cen.z == m2) { const int t = atomicAdd(&cntA, 1); if (t < SCAP) cand[t] = makekey(cen.z, cls, hwb + 2); }
        if (cen.w == m3) { const int t = atomicAdd(&cntA, 1); if (t < SCAP) cand[t] = makekey(cen.w, cls, hwb + 3); }
    }
    __syncthreads();

    // P4: write strip-B tile from regs (s reuse) + flush A keys
    {
        const int v0 = tid, v1 = tid + 256, v2 = tid + 512;
        float4 o;
        o.x = sigmoidf_(g0.x); o.y = sigmoidf_(g0.y); o.z = sigmoidf_(g0.z); o.w = sigmoidf_(g0.w);
        *reinterpret_cast<float4*>(&s[v0 >> 5][(v0 & 31) << 2]) = o;
        o.x = sigmoidf_(g1.x); o.y = sigmoidf_(g1.y); o.z = sigmoidf_(g1.z); o.w = sigmoidf_(g1.w);
        *reinterpret_cast<float4*>(&s[v1 >> 5][(v1 & 31) << 2]) = o;
        if (tid < 128) {
            o.x = sigmoidf_(g2.x); o.y = sigmoidf_(g2.y); o.z = sigmoidf_(g2.z); o.w = sigmoidf_(g2.w);
            *reinterpret_cast<float4*>(&s[v2 >> 5][(v2 & 31) << 2]) = o;
        }
    }
    {
        const int nA = cntA < SCAP ? cntA : SCAP;
        const int sgA = map * NSTRIP + 2 * pair;
        ull* __restrict__ dst = slab + (size_t)sgA * REG;
        if (nA <= REG) {
            for (int i = tid; i < nA; i += 256) dst[i] = cand[i];
            if (tid == 0) scount[sgA] = nA;
        } else {
            int n2 = 128;
            while (n2 < nA) n2 <<= 1;
            for (int i = tid; i < n2; i += 256) if (i >= nA) cand[i] = 0ULL;
            __syncthreads();
            BITONIC_DESC(cand, n2, 256);
            for (int i = tid; i < REG; i += 256) dst[i] = cand[i];
            if (tid == 0) scount[sgA] = REG;
        }
    }
    __syncthreads();

    // P5: vertical 5-max B
    for (int i = tid; i < SR * 32; i += 256) {
        const int r = i >> 5, c4 = (i & 31) << 2;
        const float4 r0 = *reinterpret_cast<const float4*>(&s[r    ][c4]);
        const float4 r1 = *reinterpret_cast<const float4*>(&s[r + 1][c4]);
        const float4 r2 = *reinterpret_cast<const float4*>(&s[r + 2][c4]);
        const float4 r3 = *reinterpret_cast<const float4*>(&s[r + 3][c4]);
        const float4 r4 = *reinterpret_cast<const float4*>(&s[r + 4][c4]);
        float4 m;
        m.x = fmaxf(fmaxf(r0.x, r1.x), fmaxf(fmaxf(r2.x, r3.x), r4.x));
        m.y = fmaxf(fmaxf(r0.y, r1.y), fmaxf(fmaxf(r2.y, r3.y), r4.y));
        m.z = fmaxf(fmaxf(r0.z, r1.z), fmaxf(fmaxf(r2.z, r3.z), r4.z));
        m.w = fmaxf(fmaxf(r0.w, r1.w), fmaxf(fmaxf(r2.w, r3.w), r4.w));
        *reinterpret_cast<float4*>(&vm[r][c4]) = m;
    }
    __syncthreads();

    // P6: horizontal 5-max B + keep + compact
    for (int i = tid; i < SR * 32; i += 256) {
        const int r = i >> 5, c4 = (i & 31) << 2;
        const float4 M = *reinterpret_cast<const float4*>(&vm[r][c4]);
        float Lz = -INFINITY, Lw = -INFINITY;
        if (c4 >= 4) {
            const float4 L = *reinterpret_cast<const float4*>(&vm[r][c4 - 4]);
            Lz = L.z; Lw = L.w;
        }
        float Rx = -INFINITY, Ry = -INFINITY;
        if (c4 <= WW - 8) {
            const float4 R = *reinterpret_cast<const float4*>(&vm[r][c4 + 4]);
            Rx = R.x; Ry = R.y;
        }
        const float4 cen = *reinterpret_cast<const float4*>(&s[r + 2][c4]);
        const float mxy = fmaxf(M.x, M.y), mzw = fmaxf(M.z, M.w);
        const float m0 = fmaxf(fmaxf(Lz, Lw), fmaxf(mxy, M.z));
        const float m1 = fmaxf(Lw, fmaxf(mxy, mzw));
        const float m2 = fmaxf(fmaxf(mxy, mzw), Rx);
        const float m3 = fmaxf(fmaxf(M.y, mzw), fmaxf(Rx, Ry));
        const int hwb = ((R0B + r) << 7) | c4;
        if (cen.x == m0) { const int t = atomicAdd(&cntB, 1); if (t < SCAP) cand[t] = makekey(cen.x, cls, hwb); }
        if (cen.y == m1) { const int t = atomicAdd(&cntB, 1); if (t < SCAP) cand[t] = makekey(cen.y, cls, hwb + 1); }
        if (cen.z == m2) { const int t = atomicAdd(&cntB, 1); if (t < SCAP) cand[t] = makekey(cen.z, cls, hwb + 2); }
        if (cen.w == m3) { const int t = atomicAdd(&cntB, 1); if (t < SCAP) cand[t] = makekey(cen.w, cls, hwb + 3); }
    }
    __syncthreads();

    // P7: flush B keys
    {
        const int nB = cntB < SCAP ? cntB : SCAP;
        const int sgB = map * NSTRIP + 2 * pair + 1;
        ull* __restrict__ dst = slab + (size_t)sgB * REG;
        if (nB <= REG) {
            for (int i = tid; i < nB; i += 256) dst[i] = cand[i];
            if (tid == 0) scount[sgB] = nB;
        } else {
            int n2 = 128;
            while (n2 < nB) n2 <<= 1;
            for (int i = tid; i < n2; i += 256) if (i >= nB) cand[i] = 0ULL;
            __syncthreads();
            BITONIC_DESC(cand, n2, 256);
            for (int i = tid; i < REG; i += 256) dst[i] = cand[i];
            if (tid == 0) scount[sgB] = REG;
        }
    }
}

// ---- in-register wave bitonic helpers (64 lanes; R6-R13 validated) ----
__device__ __forceinline__ ull sort64_desc(ull v, int lane) {
    for (int k = 2; k <= 64; k <<= 1) {
        for (int j = k >> 1; j >= 1; j >>= 1) {
            const ull p = __shfl_xor(v, j, 64);
            const bool km = (((lane & k) == 0) != ((lane & j) != 0));
            v = (km == (p > v)) ? p : v;
        }
    }
    return v;
}

__device__ __forceinline__ void bmerge128(ull& a0, ull& a1, int lane) {
    const ull t0 = a0 > a1 ? a0 : a1;
    a1 = a0 > a1 ? a1 : a0;
    a0 = t0;
    for (int j = 32; j >= 1; j >>= 1) {
        const ull p0 = __shfl_xor(a0, j, 64);
        const ull p1 = __shfl_xor(a1, j, 64);
        const bool km = ((lane & j) == 0);
        a0 = (km == (p0 > a0)) ? p0 : a0;
        a1 = (km == (p1 > a1)) ? p1 : a1;
    }
}

// ---- Kernel B: per map (640 blocks): 8 waves sort one strip each, merge -> top-128 ----
__global__ __launch_bounds__(512) void kred(const ull* __restrict__ slab,
                                            const int* __restrict__ scount,
                                            ull* __restrict__ lists) {
    __shared__ ull ls[8][128];
    const int tid = threadIdx.x, w = tid >> 6, lane = tid & 63;
    const int map = blockIdx.x;
    const int sg = map * NSTRIP + w;

    const int n = scount[sg];
    const ull* __restrict__ base = slab + (size_t)sg * REG;

    ull a0 = 0ULL, a1 = 0ULL;
#pragma unroll
    for (int c = 0; c < 2; ++c) {
        const int idx = c * 64 + lane;
        ull v = (idx < n) ? base[idx] : 0ULL;
        v = sort64_desc(v, lane);
        const ull rv = __shfl(v, 63 - lane, 64);
        a1 = a1 > rv ? a1 : rv;
        bmerge128(a0, a1, lane);
    }
    ls[w][lane] = a0;
    ls[w][64 + lane] = a1;

    for (int half = 4; half >= 1; half >>= 1) {
        __syncthreads();
        ull z0 = 0ULL, z1 = 0ULL;
        const bool act = (w < half);
        if (act) {
            const ull l0 = ls[2 * w][lane];
            const ull l1 = ls[2 * w][64 + lane];
            const ull r1r = ls[2 * w + 1][127 - lane];
            const ull r0r = ls[2 * w + 1][63 - lane];
            z0 = l0 > r1r ? l0 : r1r;
            z1 = l1 > r0r ? l1 : r0r;
            bmerge128(z0, z1, lane);
        }
        __syncthreads();
        if (act) { ls[w][lane] = z0; ls[w][64 + lane] = z1; }
    }
    __syncthreads();
    if (tid < 128)
        lists[(size_t)map * 128 + tid] = ls[0][tid];
}

// ---- Kernel C: per batch: 16 waves reg-merge 5 map-lists each, tree, decode ----
__global__ __launch_bounds__(1024) void kfin(const ull* __restrict__ lists,
                                             const float* __restrict__ txty,
                                             const float* __restrict__ twth,
                                             float* __restrict__ out) {
    __shared__ ull ls[16][128];                  // 16 KB
    const int tid = threadIdx.x, b = blockIdx.x;
    const int w = tid >> 6, lane = tid & 63;
    const ull* __restrict__ L = lists + (size_t)b * CC * 128;

    const ull* __restrict__ l0 = L + (size_t)(5 * w) * 128;
    ull a0 = l0[lane], a1 = l0[64 + lane];
#pragma unroll
    for (int k = 1; k < 5; ++k) {
        const ull* __restrict__ lk = L + (size_t)(5 * w + k) * 128;
        const ull r0 = lk[127 - lane];
        const ull r1 = lk[63 - lane];
        a0 = a0 > r0 ? a0 : r0;
        a1 = a1 > r1 ? a1 : r1;
        bmerge128(a0, a1, lane);
    }
    ls[w][lane] = a0;
    ls[w][64 + lane] = a1;

    for (int half = 8; half >= 1; half >>= 1) {
        __syncthreads();
        ull z0 = 0ULL, z1 = 0ULL;
        const bool act = (w < half);
        if (act) {
            const ull t0 = ls[2 * w][lane];
            const ull t1 = ls[2 * w][64 + lane];
            const ull r1r = ls[2 * w + 1][127 - lane];
            const ull r0r = ls[2 * w + 1][63 - lane];
            z0 = t0 > r1r ? t0 : r1r;
            z1 = t1 > r0r ? t1 : r0r;
            bmerge128(z0, z1, lane);
        }
        __syncthreads();
        if (act) { ls[w][lane] = z0; ls[w][64 + lane] = z1; }
    }
    __syncthreads();

    if (tid < KTOP) {
        const ull key = ls[0][tid];
        const int hw  = 16383 - (int)(key & 0x3FFFULL);
        const int cls = 127 - (int)((key >> 14) & 0x7FULL);
        const float sc = __uint_as_float((unsigned int)(key >> 21));

        // out layout (float32): score[0..800) | bbox[800..4000) | inds[4000..4800) | clses[4800..5600)
        out[b * KTOP + tid]        = sc;
        out[4000 + b * KTOP + tid] = (float)hw;
        out[4800 + b * KTOP + tid] = (float)cls;

        const int xx = hw & 127, yy = hw >> 7;
        const float* __restrict__ t = txty + (size_t)b * 2 * HWN;
        const float* __restrict__ u = twth + (size_t)b * 2 * HWN;
        const float tx = t[hw], ty = t[HWN + hw];
        const float tw = u[hw], th = u[HWN + hw];

        const float cx = (sigmoidf_(tx) + (float)xx) * 4.0f;
        const float cy = (sigmoidf_(ty) + (float)yy) * 4.0f;
        const float bw = expf(tw) * 4.0f;
        const float bh = expf(th) * 4.0f;

        const float inv = 1.0f / 512.0f;
        float x1 = (cx - bw * 0.5f) * inv;
        float y1 = (cy - bh * 0.5f) * inv;
        float x2 = (cx + bw * 0.5f) * inv;
        float y2 = (cy + bh * 0.5f) * inv;
        x1 = fminf(fmaxf(x1, 0.0f), 1.0f);
        y1 = fminf(fmaxf(y1, 0.0f), 1.0f);
        x2 = fminf(fmaxf(x2, 0.0f), 1.0f);
        y2 = fminf(fmaxf(y2, 0.0f), 1.0f);

        float* bb = out + 800 + (size_t)(b * KTOP + tid) * 4;
        bb[0] = x1; bb[1] = y1; bb[2] = x2; bb[3] = y2;
    }
}

extern "C" void kernel_launch(void* const* d_in, const int* in_sizes, int n_in,
                              void* d_out, int out_size, void* d_ws, size_t ws_size,
                              hipStream_t stream) {
    const float* cls_logits = (const float*)d_in[0];
    const float* txty       = (const float*)d_in[1];
    const float* twth       = (const float*)d_in[2];
    float* out = (float*)d_out;

    // ws layout (bytes):
    //   slab:   5120 strips * 100 * 8 = 4,096,000
    //   scount: 5120 * 4             =    20,480   @ 4,096,000
    //   lists:  640 * 128 * 8        =   655,360   @ 4,116,480
    ull* slab   = (ull*)d_ws;
    int* scount = (int*)((char*)d_ws + 4096000);
    ull* lists  = (ull*)((char*)d_ws + 4116480);

    knms<<<BB * CC * 4, 256, 0, stream>>>(cls_logits, slab, scount);
    kred<<<BB * CC,     512, 0, stream>>>(slab, scount, lists);
    kfin<<<BB,         1024, 0, stream>>>(lists, txty, twth, out);
}

// Round 15
// 57.235 us; speedup vs baseline: 1.0487x; 1.0044x over previous
//
#include <hip/hip_runtime.h>
#include <hip/hip_bf16.h>
#include <math.h>

#define BB   8
#define CC   80
#define HH   128
#define WW   128
#define HWN  16384
#define KTOP 100
#define NSTRIP 8
#define SR   16
#define LR   (SR + 4)
#define SCAP 512
#define REG  100        // fixed per-strip region: strip lex-top-100 superset-suffices

typedef unsigned long long ull;

__device__ __forceinline__ float sigmoidf_(float x) {
    // bitwise-matched vs jax.nn.sigmoid (R1/R3/R4/R6-R14)
    if (x >= 0.0f) return 1.0f / (1.0f + expf(-x));
    float e = expf(x);
    return e / (1.0f + e);
}

// value desc, class asc, hw asc; unique per (map,hw). Ordering == reference
// two-stage top-k (proof R2-R4, bitwise-validated through R14).
__device__ __forceinline__ ull makekey(float v, int cls, int hw) {
    return ((ull)__float_as_uint(v) << 21)
         | ((ull)(127 - cls) << 14)
         | (ull)(16383 - hw);
}

#define BITONIC_DESC(arr, N2, NTHR)                                         \
    for (int k_ = 2; k_ <= (N2); k_ <<= 1) {                                \
        for (int j_ = k_ >> 1; j_ > 0; j_ >>= 1) {                          \
            for (int i_ = threadIdx.x; i_ < (N2); i_ += (NTHR)) {           \
                const int ixj_ = i_ ^ j_;                                   \
                if (ixj_ > i_) {                                            \
                    ull a_ = (arr)[i_], b_ = (arr)[ixj_];                   \
                    if (((i_ & k_) == 0) ? (a_ < b_) : (a_ > b_)) {         \
                        (arr)[i_] = b_; (arr)[ixj_] = a_;                   \
                    }                                                       \
                }                                                           \
            }                                                               \
            __syncthreads();                                                \
        }                                                                   \
    }

// ---- Kernel A: R11 two-pass 5x5 NMS (best measured: 54.9us total) + T1 swizzle ----
// Swizzle: consecutive blockIdx round-robin across XCDs; remapping so each XCD
// owns 80 whole maps makes the 4-row strip halos L2-local (25% of tile rows).
__global__ __launch_bounds__(256) void knms(const float* __restrict__ logits,
                                            ull* __restrict__ slab,
                                            int* __restrict__ scount) {
    __shared__ __align__(16) float s[LR][WW];    // 10 KB sigmoid tile (halo-clamped)
    __shared__ __align__(16) float vm[SR][WW];   // 8 KB vertical 5-max
    __shared__ ull cand[SCAP];                   // 4 KB
    __shared__ int cnt;

    const int tid   = threadIdx.x;
    // T1 bijective XCD swizzle: 5120 blocks = 8 XCDs x 640
    const int swz   = (blockIdx.x & 7) * 640 + (blockIdx.x >> 3);
    const int map   = swz >> 3;                  // b*CC + c
    const int strip = swz & 7;
    const int cls   = map % CC;
    const int R0    = strip * SR;
    const float* __restrict__ src = logits + (size_t)map * HWN;
    if (tid == 0) cnt = 0;

    // stage sigmoid tile, float4, halo rows clamped (== -inf pad for window max)
    for (int v = tid; v < LR * 32; v += 256) {
        const int lr = v >> 5, c4 = (v & 31) << 2;
        int gr = R0 - 2 + lr;
        gr = gr < 0 ? 0 : (gr > HH - 1 ? HH - 1 : gr);
        const float4 f = *reinterpret_cast<const float4*>(src + (size_t)gr * WW + c4);
        float4 o;
        o.x = sigmoidf_(f.x); o.y = sigmoidf_(f.y);
        o.z = sigmoidf_(f.z); o.w = sigmoidf_(f.w);
        *reinterpret_cast<float4*>(&s[lr][c4]) = o;
    }
    __syncthreads();

    // vertical 5-max per column (R11-proven codegen)
    for (int i = tid; i < SR * WW; i += 256) {
        const int r = i >> 7, c = i & 127;
        float m = fmaxf(fmaxf(s[r][c], s[r + 1][c]), fmaxf(s[r + 2][c], s[r + 3][c]));
        vm[r][c] = fmaxf(m, s[r + 4][c]);
    }
    __syncthreads();

    // horizontal 5-max + keep + block compact
    for (int i = tid; i < SR * WW; i += 256) {
        const int r = i >> 7, c = i & 127;
        const int cm2 = c - 2 < 0 ? 0 : c - 2;
        const int cm1 = c - 1 < 0 ? 0 : c - 1;
        const int cp1 = c + 1 > 127 ? 127 : c + 1;
        const int cp2 = c + 2 > 127 ? 127 : c + 2;
        float m = fmaxf(fmaxf(vm[r][cm2], vm[r][cm1]), fmaxf(vm[r][c], vm[r][cp1]));
        m = fmaxf(m, vm[r][cp2]);
        const float v = s[r + 2][c];
        if (v == m) {   // exact reference keep: sigma == 5x5 sigma-max
            const int slot = atomicAdd(&cnt, 1);
            if (slot < SCAP) cand[slot] = makekey(v, cls, ((R0 + r) << 7) | c);
        }
    }
    __syncthreads();

    const int n = cnt < SCAP ? cnt : SCAP;
    ull* __restrict__ dst = slab + (size_t)swz * REG;
    if (n <= REG) {
        // fast path (n~82): unsorted write + count — no global atomics (R11 lesson)
        for (int i = tid; i < n; i += 256) dst[i] = cand[i];
        if (tid == 0) scount[swz] = n;
    } else {
        // rare path: exact lex-top-100 via in-LDS bitonic (R4-proven)
        int n2 = 128;
        while (n2 < n) n2 <<= 1;
        for (int i = tid; i < n2; i += 256) if (i >= n) cand[i] = 0ULL;
        __syncthreads();
        BITONIC_DESC(cand, n2, 256);
        for (int i = tid; i < REG; i += 256) dst[i] = cand[i];
        if (tid == 0) scount[swz] = REG;
    }
}

// ---- in-register wave bitonic helpers (64 lanes; R6-R14 validated) ----
__device__ __forceinline__ ull sort64_desc(ull v, int lane) {
    for (int k = 2; k <= 64; k <<= 1) {
        for (int j = k >> 1; j >= 1; j >>= 1) {
            const ull p = __shfl_xor(v, j, 64);
            const bool km = (((lane & k) == 0) != ((lane & j) != 0));
            v = (km == (p > v)) ? p : v;
        }
    }
    return v;
}

__device__ __forceinline__ void bmerge128(ull& a0, ull& a1, int lane) {
    const ull t0 = a0 > a1 ? a0 : a1;
    a1 = a0 > a1 ? a1 : a0;
    a0 = t0;
    for (int j = 32; j >= 1; j >>= 1) {
        const ull p0 = __shfl_xor(a0, j, 64);
        const ull p1 = __shfl_xor(a1, j, 64);
        const bool km = ((lane & j) == 0);
        a0 = (km == (p0 > a0)) ? p0 : a0;
        a1 = (km == (p1 > a1)) ? p1 : a1;
    }
}

// ---- Kernel B: per map (640 blocks): 8 waves sort one strip each, merge -> top-128 ----
__global__ __launch_bounds__(512) void kred(const ull* __restrict__ slab,
                                            const int* __restrict__ scount,
                                            ull* __restrict__ lists) {
    __shared__ ull ls[8][128];
    const int tid = threadIdx.x, w = tid >> 6, lane = tid & 63;
    const int map = blockIdx.x;
    const int sg = map * NSTRIP + w;             // global strip id for this wave

    const int n = scount[sg];
    const ull* __restrict__ base = slab + (size_t)sg * REG;

    ull a0 = 0ULL, a1 = 0ULL;
#pragma unroll
    for (int c = 0; c < 2; ++c) {
        const int idx = c * 64 + lane;
        ull v = (idx < n) ? base[idx] : 0ULL;
        v = sort64_desc(v, lane);
        const ull rv = __shfl(v, 63 - lane, 64);
        a1 = a1 > rv ? a1 : rv;
        bmerge128(a0, a1, lane);
    }
    ls[w][lane] = a0;
    ls[w][64 + lane] = a1;

    for (int half = 4; half >= 1; half >>= 1) {
        __syncthreads();
        ull z0 = 0ULL, z1 = 0ULL;
        const bool act = (w < half);
        if (act) {
            const ull l0 = ls[2 * w][lane];
            const ull l1 = ls[2 * w][64 + lane];
            const ull r1r = ls[2 * w + 1][127 - lane];
            const ull r0r = ls[2 * w + 1][63 - lane];
            z0 = l0 > r1r ? l0 : r1r;
            z1 = l1 > r0r ? l1 : r0r;
            bmerge128(z0, z1, lane);
        }
        __syncthreads();
        if (act) { ls[w][lane] = z0; ls[w][64 + lane] = z1; }
    }
    __syncthreads();
    if (tid < 128)
        lists[(size_t)map * 128 + tid] = ls[0][tid];
}

// ---- Kernel C: per batch: 16 waves reg-merge 5 map-lists each, tree, decode ----
__global__ __launch_bounds__(1024) void kfin(const ull* __restrict__ lists,
                                             const float* __restrict__ txty,
                                             const float* __restrict__ twth,
                                             float* __restrict__ out) {
    __shared__ ull ls[16][128];                  // 16 KB
    const int tid = threadIdx.x, b = blockIdx.x;
    const int w = tid >> 6, lane = tid & 63;
    const ull* __restrict__ L = lists + (size_t)b * CC * 128;

    const ull* __restrict__ l0 = L + (size_t)(5 * w) * 128;
    ull a0 = l0[lane], a1 = l0[64 + lane];
#pragma unroll
    for (int k = 1; k < 5; ++k) {
        const ull* __restrict__ lk = L + (size_t)(5 * w + k) * 128;
        const ull r0 = lk[127 - lane];
        const ull r1 = lk[63 - lane];
        a0 = a0 > r0 ? a0 : r0;
        a1 = a1 > r1 ? a1 : r1;
        bmerge128(a0, a1, lane);
    }
    ls[w][lane] = a0;
    ls[w][64 + lane] = a1;

    for (int half = 8; half >= 1; half >>= 1) {
        __syncthreads();
        ull z0 = 0ULL, z1 = 0ULL;
        const bool act = (w < half);
        if (act) {
            const ull t0 = ls[2 * w][lane];
            const ull t1 = ls[2 * w][64 + lane];
            const ull r1r = ls[2 * w + 1][127 - lane];
            const ull r0r = ls[2 * w + 1][63 - lane];
            z0 = t0 > r1r ? t0 : r1r;
            z1 = t1 > r0r ? t1 : r0r;
            bmerge128(z0, z1, lane);
        }
        __syncthreads();
        if (act) { ls[w][lane] = z0; ls[w][64 + lane] = z1; }
    }
    __syncthreads();

    if (tid < KTOP) {
        const ull key = ls[0][tid];
        const int hw  = 16383 - (int)(key & 0x3FFFULL);
        const int cls = 127 - (int)((key >> 14) & 0x7FULL);
        const float sc = __uint_as_float((unsigned int)(key >> 21));

        // out layout (float32): score[0..800) | bbox[800..4000) | inds[4000..4800) | clses[4800..5600)
        out[b * KTOP + tid]        = sc;
        out[4000 + b * KTOP + tid] = (float)hw;
        out[4800 + b * KTOP + tid] = (float)cls;

        const int xx = hw & 127, yy = hw >> 7;
        const float* __restrict__ t = txty + (size_t)b * 2 * HWN;
        const float* __restrict__ u = twth + (size_t)b * 2 * HWN;
        const float tx = t[hw], ty = t[HWN + hw];
        const float tw = u[hw], th = u[HWN + hw];

        const float cx = (sigmoidf_(tx) + (float)xx) * 4.0f;
        const float cy = (sigmoidf_(ty) + (float)yy) * 4.0f;
        const float bw = expf(tw) * 4.0f;
        const float bh = expf(th) * 4.0f;

        const float inv = 1.0f / 512.0f;
        float x1 = (cx - bw * 0.5f) * inv;
        float y1 = (cy - bh * 0.5f) * inv;
        float x2 = (cx + bw * 0.5f) * inv;
        float y2 = (cy + bh * 0.5f) * inv;
        x1 = fminf(fmaxf(x1, 0.0f), 1.0f);
        y1 = fminf(fmaxf(y1, 0.0f), 1.0f);
        x2 = fminf(fmaxf(x2, 0.0f), 1.0f);
        y2 = fminf(fmaxf(y2, 0.0f), 1.0f);

        float* bb = out + 800 + (size_t)(b * KTOP + tid) * 4;
        bb[0] = x1; bb[1] = y1; bb[2] = x2; bb[3] = y2;
    }
}

extern "C" void kernel_launch(void* const* d_in, const int* in_sizes, int n_in,
                              void* d_out, int out_size, void* d_ws, size_t ws_size,
                              hipStream_t stream) {
    const float* cls_logits = (const float*)d_in[0];
    const float* txty       = (const float*)d_in[1];
    const float* twth       = (const float*)d_in[2];
    float* out = (float*)d_out;

    // ws layout (bytes):
    //   slab:   5120 strips * 100 * 8 = 4,096,000
    //   scount: 5120 * 4             =    20,480   @ 4,096,000
    //   lists:  640 * 128 * 8        =   655,360   @ 4,116,480
    // total 4,771,840 — every byte read is written first (no memset needed)
    ull* slab   = (ull*)d_ws;
    int* scount = (int*)((char*)d_ws + 4096000);
    ull* lists  = (ull*)((char*)d_ws + 4116480);

    knms<<<BB * CC * NSTRIP, 256, 0, stream>>>(cls_logits, slab, scount);
    kred<<<BB * CC,          512, 0, stream>>>(slab, scount, lists);
    kfin<<<BB,              1024, 0, stream>>>(lists, txty, twth, out);
}